// Round 7
// baseline (322.558 us; speedup 1.0000x reference)
//
#include <hip/hip_runtime.h>

// z[b,d] = x[b,d] * (1 + sum_{i=1..K} w[i-1,d] * x[b,(d+i) mod D])
// B=8192, D=4096, K=16, fp32. HBM floor: ~204 MB real traffic -> ~32 us.
//
// Plateau history: R2(86) R6(86) R7(90) = LDS-staged, three different
//   barrier schedules, identical perf. Per-CU tile arithmetic: LDS unit is
//   ~66% busy (5x read amplification: 320KB ds_read + 80KB gld_lds-write
//   per 36KB HBM) + barrier quantization -> LDS staging is the structural
//   cost, not the barrier flavor. R4(187): no w reuse -> 16 w loads/output
//   thrash L1 (w footprint 256KB/CU >> 32KB L1). R3(96)/R5(119): reg
//   pipelines; compiler remat'd/spilled the 64-reg wv array (VGPR 68/60).
//   R7 proved in-loop asm pins DO hold wv (VGPR=84, no scratch traffic).
// R8 (this): copy-kernel shape. NO LDS, NO barriers. Plain global float4
//   loads (L1 absorbs the 5x overlap at full L1 BW - proven by R4 where x
//   pattern was fine); w held in 64 VGPRs across 32 rows with the R7 pin;
//   pure TLP (16 waves/CU, each with 5KB in flight while stalled - the m13
//   6.3 TB/s regime). nt stores keep x L3-resident.

#define D 4096
#define DG 1024          // D/4 float4 column-groups per row
#define K 16
#define TPB 256
#define RPB 32           // rows per block -> grid (4, 256) = 1024 blocks

typedef float f32x4 __attribute__((ext_vector_type(4)));

__global__ __launch_bounds__(TPB) void quad_enhancer_kernel(
    const float* __restrict__ x, const float* __restrict__ w,
    float* __restrict__ out) {
  const int tid = threadIdx.x;
  const int cg = blockIdx.x * TPB + tid;  // this thread's column-group
  const int b0 = blockIdx.y * RPB;

  const float4* __restrict__ x4 = (const float4*)x;
  const float4* __restrict__ w4 = (const float4*)w;
  f32x4* __restrict__ o4 = (f32x4*)out;

  // Neighbor groups with wrap (only cg >= DG-4 actually wraps).
  const int g1 = (cg + 1) & (DG - 1);
  const int g2 = (cg + 2) & (DG - 1);
  const int g3 = (cg + 3) & (DG - 1);
  const int g4 = (cg + 4) & (DG - 1);

  // w[:, 4cg..4cg+3] in 64 VGPRs, reused for all RPB rows.
  float4 wv[K];
#pragma unroll
  for (int i = 0; i < K; ++i) wv[i] = w4[i * DG + cg];

  const float4* __restrict__ xr = x4 + (size_t)b0 * DG;
  f32x4* __restrict__ orow = o4 + (size_t)b0 * DG;

#pragma unroll 1
  for (int r = 0; r < RPB; ++r) {
    // R7-proven pin: force wv live in VGPRs every iteration -> compiler
    // cannot rematerialize (reload) or spill them across the loop.
#pragma unroll
    for (int i = 0; i < K; ++i) {
      asm volatile("" : "+v"(wv[i].x), "+v"(wv[i].y), "+v"(wv[i].z),
                        "+v"(wv[i].w));
    }

    // 5 independent coalesced loads (20 consecutive floats); 4/5 hit L1.
    // All issued back-to-back -> 5KB/wave in flight under one waitcnt.
    float4 v0 = xr[cg];
    float4 v1 = xr[g1];
    float4 v2 = xr[g2];
    float4 v3 = xr[g3];
    float4 v4 = xr[g4];

    float xs[20];
    xs[0] = v0.x;  xs[1] = v0.y;  xs[2] = v0.z;  xs[3] = v0.w;
    xs[4] = v1.x;  xs[5] = v1.y;  xs[6] = v1.z;  xs[7] = v1.w;
    xs[8] = v2.x;  xs[9] = v2.y;  xs[10] = v2.z; xs[11] = v2.w;
    xs[12] = v3.x; xs[13] = v3.y; xs[14] = v3.z; xs[15] = v3.w;
    xs[16] = v4.x; xs[17] = v4.y; xs[18] = v4.z; xs[19] = v4.w;

    float ax = 1.0f, ay = 1.0f, az = 1.0f, aw = 1.0f;
#pragma unroll
    for (int i = 0; i < K; ++i) {
      ax = fmaf(wv[i].x, xs[i + 1], ax);
      ay = fmaf(wv[i].y, xs[i + 2], ay);
      az = fmaf(wv[i].z, xs[i + 3], az);
      aw = fmaf(wv[i].w, xs[i + 4], aw);
    }

    f32x4 o;
    o.x = xs[0] * ax;
    o.y = xs[1] * ay;
    o.z = xs[2] * az;
    o.w = xs[3] * aw;
    __builtin_nontemporal_store(o, &orow[cg]);

    xr += DG;
    orow += DG;
  }
}

extern "C" void kernel_launch(void* const* d_in, const int* in_sizes, int n_in,
                              void* d_out, int out_size, void* d_ws, size_t ws_size,
                              hipStream_t stream) {
  const float* x = (const float*)d_in[0];
  const float* w = (const float*)d_in[1];
  float* out = (float*)d_out;
  const int B = in_sizes[0] / D;  // 8192

  dim3 grid(DG / TPB, B / RPB);   // (4, 256) = 1024 blocks, 4/CU
  quad_enhancer_kernel<<<grid, TPB, 0, stream>>>(x, w, out);
}

// Round 8
// 321.837 us; speedup vs baseline: 1.0022x; 1.0022x over previous
//
#include <hip/hip_runtime.h>

// z[b,d] = x[b,d] * (1 + sum_{i=1..K} w[i-1,d] * x[b,(d+i) mod D])
// B=8192, D=4096, K=16, fp32. HBM floor: ~204 MB real traffic -> ~32 us.
//
// Session findings:
// - LDS-staged (R2/R6/R7, 86-90 us): LDS unit ~66% busy from 5x read
//   amplification + barrier quantization. Structural cap, not schedule.
// - No w reuse (R4, 187 us): 16 w loads/output thrash L1. Mandatory reuse.
// - Reg-resident shape (R3/R5/R8): compiler remat'd (VGPR=68), spilled
//   (60), or pinned-but-serialized (68, 11% VALU, 1.2 TB/s). ROOT CAUSE:
//   hipcc's default regalloc targets max-occupancy (~64 VGPR) and
//   sacrifices ILP to get there. R1 datapoint: launch_bounds(256,4) ->
//   64-reg cap. Never told the allocator the budget.
// R9 (this) = R8 + __launch_bounds__(256, 2): 2 waves/EU -> ~128-reg
//   budget. wv[16] (64) + xs (20) + load bufs + addressing fits without
//   remat/spill/serialization. 8 waves/CU x 5KB in flight x ~84% duty
//   ~= 30KB outstanding/CU >> ~10-17KB needed for 6 TB/s.

#define D 4096
#define DG 1024          // D/4 float4 column-groups per row
#define K 16
#define TPB 256
#define RPB 32           // rows per block -> grid (4, 256) = 1024 blocks

typedef float f32x4 __attribute__((ext_vector_type(4)));

__global__ __launch_bounds__(TPB, 2) void quad_enhancer_kernel(
    const float* __restrict__ x, const float* __restrict__ w,
    float* __restrict__ out) {
  const int tid = threadIdx.x;
  const int cg = blockIdx.x * TPB + tid;  // this thread's column-group
  const int b0 = blockIdx.y * RPB;

  const float4* __restrict__ x4 = (const float4*)x;
  const float4* __restrict__ w4 = (const float4*)w;

  // Neighbor groups with wrap (only cg >= DG-4 actually wraps).
  const int g1 = (cg + 1) & (DG - 1);
  const int g2 = (cg + 2) & (DG - 1);
  const int g3 = (cg + 3) & (DG - 1);
  const int g4 = (cg + 4) & (DG - 1);

  // w[:, 4cg..4cg+3] in 64 VGPRs, reused for all RPB rows.
  float4 wv[K];
#pragma unroll
  for (int i = 0; i < K; ++i) wv[i] = w4[i * DG + cg];

  const float4* __restrict__ xr = x4 + (size_t)b0 * DG;
  f32x4* __restrict__ orow = (f32x4*)out + (size_t)b0 * DG;

#pragma unroll 1
  for (int r = 0; r < RPB; ++r) {
    // Pin wv live every iteration (R7-proven against remat; now the
    // launch_bounds budget means the allocator need not fight it).
#pragma unroll
    for (int i = 0; i < K; ++i) {
      asm volatile("" : "+v"(wv[i].x), "+v"(wv[i].y), "+v"(wv[i].z),
                        "+v"(wv[i].w));
    }

    // 5 independent coalesced loads (20 consecutive floats); 4/5 hit L1.
    // With ~128-reg budget all 5 stay in flight under one waitcnt.
    float4 v0 = xr[cg];
    float4 v1 = xr[g1];
    float4 v2 = xr[g2];
    float4 v3 = xr[g3];
    float4 v4 = xr[g4];

    float xs[20];
    xs[0] = v0.x;  xs[1] = v0.y;  xs[2] = v0.z;  xs[3] = v0.w;
    xs[4] = v1.x;  xs[5] = v1.y;  xs[6] = v1.z;  xs[7] = v1.w;
    xs[8] = v2.x;  xs[9] = v2.y;  xs[10] = v2.z; xs[11] = v2.w;
    xs[12] = v3.x; xs[13] = v3.y; xs[14] = v3.z; xs[15] = v3.w;
    xs[16] = v4.x; xs[17] = v4.y; xs[18] = v4.z; xs[19] = v4.w;

    float ax = 1.0f, ay = 1.0f, az = 1.0f, aw = 1.0f;
#pragma unroll
    for (int i = 0; i < K; ++i) {
      ax = fmaf(wv[i].x, xs[i + 1], ax);
      ay = fmaf(wv[i].y, xs[i + 2], ay);
      az = fmaf(wv[i].z, xs[i + 3], az);
      aw = fmaf(wv[i].w, xs[i + 4], aw);
    }

    f32x4 o;
    o.x = xs[0] * ax;
    o.y = xs[1] * ay;
    o.z = xs[2] * az;
    o.w = xs[3] * aw;
    __builtin_nontemporal_store(o, &orow[cg]);

    xr += DG;
    orow += DG;
  }
}

extern "C" void kernel_launch(void* const* d_in, const int* in_sizes, int n_in,
                              void* d_out, int out_size, void* d_ws, size_t ws_size,
                              hipStream_t stream) {
  const float* x = (const float*)d_in[0];
  const float* w = (const float*)d_in[1];
  float* out = (float*)d_out;
  const int B = in_sizes[0] / D;  // 8192

  dim3 grid(DG / TPB, B / RPB);   // (4, 256) = 1024 blocks
  quad_enhancer_kernel<<<grid, TPB, 0, stream>>>(x, w, out);
}